// Round 4
// baseline (132.103 us; speedup 1.0000x reference)
//
#include <hip/hip_runtime.h>

#define DD 128
#define BM 64
#define T_TYPES 16

typedef __bf16 bf16x8 __attribute__((ext_vector_type(8)));
typedef __bf16 bf16x4 __attribute__((ext_vector_type(4)));
typedef float  f32x4  __attribute__((ext_vector_type(4)));

// async 16B global -> LDS DMA (no VGPR round-trip). LDS dest is
// wave-uniform base + lane*16; our layouts are contiguous in lane order.
__device__ __forceinline__ void async_copy16(const void* g, void* l) {
    __builtin_amdgcn_global_load_lds(
        (const __attribute__((address_space(1))) unsigned int*)g,
        (__attribute__((address_space(3))) unsigned int*)l, 16, 0, 0);
}

// ---------- Pre-kernel: w fp32 [t][k][n] -> bf16 MFMA-fragment order ----------
// wbf layout: [t][nt(8)][kk(4)][lane(64)][j(8)] bf16; B-fragment for (nt,kk)
// held by lane(q=lane>>4,n16=lane&15) is B[k=kk*32+q*8+j][n=nt*16+n16].
// Linear in exactly the order the main kernel's waves consume it.
__global__ __launch_bounds__(256) void transpose_w_frag_kernel(
    const float* __restrict__ w, unsigned short* __restrict__ wbf)
{
    __shared__ float lds[DD * 33];            // [k][n-local 32 + pad]
    const int t   = blockIdx.x >> 2;
    const int n0  = (blockIdx.x & 3) * 32;
    const int tid = threadIdx.x;
    const float* wt = w + (size_t)t * DD * DD;

    #pragma unroll
    for (int i = 0; i < 4; ++i) {             // coalesced float4 reads
        int f = tid + i * 256;
        int k = f >> 3;
        int c = (f & 7) * 4;
        float4 v = *(const float4*)&wt[k * DD + n0 + c];
        lds[k * 33 + c + 0] = v.x;
        lds[k * 33 + c + 1] = v.y;
        lds[k * 33 + c + 2] = v.z;
        lds[k * 33 + c + 3] = v.w;
    }
    __syncthreads();
    #pragma unroll
    for (int i = 0; i < 4; ++i) {
        int g  = tid + i * 256;
        int nl = g >> 5;                       // n-local 0..31
        int k4 = (g & 31) * 4;                 // k step 4 (stays within one q)
        int n  = n0 + nl;
        int nt  = n >> 4, n16 = n & 15;
        int kk  = k4 >> 5, q = (k4 >> 3) & 3, jb = k4 & 7;
        int lane = q * 16 + n16;
        size_t ofs = ((((size_t)t * 8 + nt) * 4 + kk) * 64 + lane) * 8 + jb;
        ushort4 o;
        union { __bf16 b; unsigned short u; } cv;
        cv.b = (__bf16)lds[(k4 + 0) * 33 + nl]; o.x = cv.u;
        cv.b = (__bf16)lds[(k4 + 1) * 33 + nl]; o.y = cv.u;
        cv.b = (__bf16)lds[(k4 + 2) * 33 + nl]; o.z = cv.u;
        cv.b = (__bf16)lds[(k4 + 3) * 33 + nl]; o.w = cv.u;
        *(ushort4*)&wbf[ofs] = o;
    }
}

// ---------- Main kernel ----------
// B (W fragments) arrive in LDS via async DMA (zero VGPR cost); A (x rows)
// staged fp32->bf16 in swizzled LDS; MFMA reads both via ds_read_b128.
__global__ __launch_bounds__(256, 3) void hetero_main_kernel(
    const float* __restrict__ x,
    const int*   __restrict__ tv,
    const __bf16* __restrict__ wbf,   // fragment-ordered bf16 W
    const float* __restrict__ bias,   // [T][128]
    float*       __restrict__ out)    // [N][128]
{
    __shared__ __bf16 As[BM * DD];    // 16 KB, swizzled granules
    __shared__ __bf16 Bs[DD * DD];    // 32 KB, fragment order [frag(32)][lane(64)][8]

    const int tid  = threadIdx.x;
    const int wave = tid >> 6;
    const int lane = tid & 63;
    const int q    = lane >> 4;
    const int n16  = lane & 15;
    const int row0 = blockIdx.x * BM;

    const int t0 = tv[row0];
    const int t1 = tv[row0 + BM - 1];
    const bool uniform = (t0 == t1);

    // ---- Issue W[t0] DMA first: 32 KB, contiguous, 8 insts/wave, no VGPRs ----
    {
        const char* gsrc = (const char*)(wbf + (size_t)t0 * DD * DD);
        char* ldst = (char*)Bs;
        const int wbyte = wave * 1024;          // wave-uniform LDS base piece
        const int gofs  = tid * 16;
        #pragma unroll
        for (int r = 0; r < 8; ++r)
            async_copy16(gsrc + r * 4096 + gofs, ldst + r * 4096 + wbyte);
    }

    // ---- Stage A: coalesced float4 reads -> bf16 -> swizzled LDS ----
    {
        const float4* xg = (const float4*)(x + (size_t)row0 * DD);
        #pragma unroll
        for (int i = 0; i < 8; ++i) {
            int f  = tid + i * 256;
            int r  = f >> 5;                 // 32 float4 per row
            int c4 = (f & 31) << 2;
            float4 v = xg[f];
            bf16x4 pk;
            pk[0] = (__bf16)v.x; pk[1] = (__bf16)v.y;
            pk[2] = (__bf16)v.z; pk[3] = (__bf16)v.w;
            int g = c4 >> 3;                 // 16B granule
            *(bf16x4*)&As[r * DD + ((g ^ (r & 7)) << 3) + (c4 & 7)] = pk;
        }
    }
    __syncthreads();   // drains DMA (vmcnt) + As writes (lgkmcnt)

    // ---- A fragments: A[m=wave*16+n16][k=kk*32+q*8+j], swizzle-corrected ----
    bf16x8 a[4];
    {
        const __bf16* arow = &As[(wave * 16 + n16) * DD];
        #pragma unroll
        for (int kk = 0; kk < 4; ++kk) {
            int gr = ((kk << 2) | q) ^ (n16 & 7);
            a[kk] = *(const bf16x8*)&arow[gr << 3];
        }
    }

    for (int t = t0; t <= t1; ++t) {
        if (t > t0) {                        // rare: block spans types
            __syncthreads();                 // all waves done reading old Bs
            const char* gsrc = (const char*)(wbf + (size_t)t * DD * DD);
            char* ldst = (char*)Bs;
            const int wbyte = wave * 1024;
            const int gofs  = tid * 16;
            #pragma unroll
            for (int r = 0; r < 8; ++r)
                async_copy16(gsrc + r * 4096 + gofs, ldst + r * 4096 + wbyte);
            __syncthreads();
        }

        f32x4 acc[8];
        #pragma unroll
        for (int nt = 0; nt < 8; ++nt) acc[nt] = (f32x4){0.f, 0.f, 0.f, 0.f};

        // B fragments: ds_read_b128, lane-contiguous (conflict-free b128 order)
        #pragma unroll
        for (int nt = 0; nt < 8; ++nt) {
            #pragma unroll
            for (int kk = 0; kk < 4; ++kk) {
                bf16x8 b = *(const bf16x8*)&Bs[(((nt << 2) | kk) << 9) + (lane << 3)];
                acc[nt] = __builtin_amdgcn_mfma_f32_16x16x32_bf16(a[kk], b, acc[nt], 0, 0, 0);
            }
        }

        // ---- Epilogue: D[row=q*4+reg][col=nt*16+n16]; lane-contiguous stores ----
        const int rbase = row0 + wave * 16 + q * 4;
        bool m0 = true, m1 = true, m2 = true, m3 = true;
        if (!uniform) {
            m0 = (tv[rbase + 0] == t);
            m1 = (tv[rbase + 1] == t);
            m2 = (tv[rbase + 2] == t);
            m3 = (tv[rbase + 3] == t);
        }
        #pragma unroll
        for (int nt = 0; nt < 8; ++nt) {
            int   col = nt * 16 + n16;
            float bv  = bias[t * DD + col];
            float* o  = out + (size_t)rbase * DD + col;
            if (m0) o[0 * DD] = acc[nt][0] + bv;
            if (m1) o[1 * DD] = acc[nt][1] + bv;
            if (m2) o[2 * DD] = acc[nt][2] + bv;
            if (m3) o[3 * DD] = acc[nt][3] + bv;
        }
    }
}

extern "C" void kernel_launch(void* const* d_in, const int* in_sizes, int n_in,
                              void* d_out, int out_size, void* d_ws, size_t ws_size,
                              hipStream_t stream) {
    const float* x    = (const float*)d_in[0];
    const int*   tv   = (const int*)d_in[1];
    const float* w    = (const float*)d_in[2];
    const float* bias = (const float*)d_in[3];
    float*       out  = (float*)d_out;
    unsigned short* wbf = (unsigned short*)d_ws;   // 16*128*128*2 = 512 KB

    int nrows = in_sizes[0] / DD;                  // 131072
    int grid  = nrows / BM;                        // 2048

    hipLaunchKernelGGL(transpose_w_frag_kernel, dim3(T_TYPES * 4), dim3(256), 0, stream,
                       w, wbf);
    hipLaunchKernelGGL(hetero_main_kernel, dim3(grid), dim3(256), 0, stream,
                       x, tv, (const __bf16*)wbf, bias, out);
}

// Round 5
// 122.518 us; speedup vs baseline: 1.0782x; 1.0782x over previous
//
#include <hip/hip_runtime.h>

#define DD 128
#define BM 64
#define CHUNK 4          // tiles per block -> 256 contiguous rows/block, grid 512
#define T_TYPES 16

typedef __bf16 bf16x8 __attribute__((ext_vector_type(8)));
typedef __bf16 bf16x4 __attribute__((ext_vector_type(4)));
typedef float  f32x4  __attribute__((ext_vector_type(4)));

// async 16B global->LDS DMA: per-lane global addr, wave-uniform LDS base,
// HW scatters lane i at base + i*16.
__device__ __forceinline__ void async_copy16(const void* g, void* l) {
    __builtin_amdgcn_global_load_lds(
        (const __attribute__((address_space(1))) unsigned int*)g,
        (__attribute__((address_space(3))) unsigned int*)l, 16, 0, 0);
}

// ---------- Pre-kernel: w fp32 [t][k][n] -> bf16 MFMA-fragment order ----------
// wbf layout: [t][nt(8)][kk(4)][lane(64)][j(8)] bf16; B-fragment for (nt,kk)
// held by lane(q,n16) is B[k=kk*32+q*8+j][n=nt*16+n16] = w[t][k][n].
__global__ __launch_bounds__(256) void transpose_w_frag_kernel(
    const float* __restrict__ w, unsigned short* __restrict__ wbf)
{
    __shared__ float lds[DD * 33];
    const int t   = blockIdx.x >> 2;
    const int n0  = (blockIdx.x & 3) * 32;
    const int tid = threadIdx.x;
    const float* wt = w + (size_t)t * DD * DD;

    #pragma unroll
    for (int i = 0; i < 4; ++i) {
        int f = tid + i * 256;
        int k = f >> 3;
        int c = (f & 7) * 4;
        float4 v = *(const float4*)&wt[k * DD + n0 + c];
        lds[k * 33 + c + 0] = v.x;
        lds[k * 33 + c + 1] = v.y;
        lds[k * 33 + c + 2] = v.z;
        lds[k * 33 + c + 3] = v.w;
    }
    __syncthreads();
    #pragma unroll
    for (int i = 0; i < 4; ++i) {
        int g  = tid + i * 256;
        int nl = g >> 5;
        int k4 = (g & 31) * 4;
        int n  = n0 + nl;
        int nt  = n >> 4, n16 = n & 15;
        int kk  = k4 >> 5, q = (k4 >> 3) & 3, jb = k4 & 7;
        int lane = q * 16 + n16;
        size_t ofs = ((((size_t)t * 8 + nt) * 4 + kk) * 64 + lane) * 8 + jb;
        ushort4 o;
        union { __bf16 b; unsigned short u; } cv;
        cv.b = (__bf16)lds[(k4 + 0) * 33 + nl]; o.x = cv.u;
        cv.b = (__bf16)lds[(k4 + 1) * 33 + nl]; o.y = cv.u;
        cv.b = (__bf16)lds[(k4 + 2) * 33 + nl]; o.z = cv.u;
        cv.b = (__bf16)lds[(k4 + 3) * 33 + nl]; o.w = cv.u;
        *(ushort4*)&wbf[ofs] = o;
    }
}

// ---------- Main kernel: persistent 4-tile blocks, pipelined, barrier-free ----------
__global__ __launch_bounds__(256, 2) void hetero_main_kernel(
    const float* __restrict__ x,
    const int*   __restrict__ tv,
    const __bf16* __restrict__ wbf,   // fragment-ordered bf16 W
    const float* __restrict__ bias,   // [T][128]
    float*       __restrict__ out)    // [N][128]
{
    __shared__ __bf16 As[4 * 16 * DD];   // 4 per-wave private quadrants (16 KB)
    __shared__ __bf16 Bs[DD * DD];       // 32 KB, fragment order

    const int tid  = threadIdx.x;
    const int wave = tid >> 6;
    const int lane = tid & 63;
    const int q    = lane >> 4;
    const int n16  = lane & 15;
    const int chunk0 = blockIdx.x * (BM * CHUNK);

    __bf16* Aq = &As[wave * 16 * DD];

    int t_res = tv[chunk0];

    // ---- W[t_res] -> Bs: 8 async DMA insts/wave, zero VGPR cost ----
    {
        const char* gsrc = (const char*)(wbf + (size_t)t_res * DD * DD);
        char* ldst = (char*)Bs;
        const int wofs = wave * 1024 + lane * 16;
        #pragma unroll
        for (int r = 0; r < 8; ++r)
            async_copy16(gsrc + r * 4096 + wofs, ldst + r * 4096 + wave * 1024);
    }

    // bias cached in regs for resident type
    float bv[8];
    #pragma unroll
    for (int nt = 0; nt < 8; ++nt) bv[nt] = bias[t_res * DD + nt * 16 + n16];

    // ---- prefetch x tile 0 (wave's own 16 rows, perfectly coalesced) ----
    float4 xf[8];
    {
        const float4* p = (const float4*)(x + (size_t)(chunk0 + wave * 16) * DD);
        #pragma unroll
        for (int j = 0; j < 8; ++j) xf[j] = p[lane + 64 * j];
    }

    __syncthreads();   // drain W DMA (all waves read all of Bs)

    #pragma unroll
    for (int tile = 0; tile < CHUNK; ++tile) {
        const int trow0 = chunk0 + tile * BM;
        const int wrow0 = trow0 + wave * 16;

        // issue next tile's prefetch first -> loads fly under this tile's compute
        float4 xn[8];
        if (tile + 1 < CHUNK) {
            const float4* p = (const float4*)(x + (size_t)(wrow0 + BM) * DD);
            #pragma unroll
            for (int j = 0; j < 8; ++j) xn[j] = p[lane + 64 * j];
        }

        // stage current tile into this wave's LDS quadrant (swizzled granules).
        // Same-wave DS ordering => no barrier needed anywhere on the A path.
        #pragma unroll
        for (int j = 0; j < 8; ++j) {
            int f  = lane + 64 * j;
            int r  = f >> 5;
            int c4 = (f & 31) << 2;
            int g  = c4 >> 3;
            bf16x4 pk;
            pk[0] = (__bf16)xf[j].x; pk[1] = (__bf16)xf[j].y;
            pk[2] = (__bf16)xf[j].z; pk[3] = (__bf16)xf[j].w;
            *(bf16x4*)&Aq[r * DD + (((g ^ (r & 7)) << 3) | (c4 & 7))] = pk;
        }

        // A fragments: A[m=n16][k=kk*32+q*8+j], swizzle-corrected
        bf16x8 a[4];
        #pragma unroll
        for (int kk = 0; kk < 4; ++kk) {
            int gr = ((kk << 2) | q) ^ (n16 & 7);
            a[kk] = *(const bf16x8*)&Aq[n16 * DD + (gr << 3)];
        }

        const int tlo = tv[trow0];
        const int thi = tv[trow0 + BM - 1];

        for (int t = tlo; t <= thi; ++t) {
            if (t != t_res) {               // rare: block-uniform branch
                __syncthreads();            // all waves done reading old Bs
                const char* gsrc = (const char*)(wbf + (size_t)t * DD * DD);
                char* ldst = (char*)Bs;
                const int wofs = wave * 1024 + lane * 16;
                #pragma unroll
                for (int r = 0; r < 8; ++r)
                    async_copy16(gsrc + r * 4096 + wofs, ldst + r * 4096 + wave * 1024);
                t_res = t;
                #pragma unroll
                for (int nt = 0; nt < 8; ++nt) bv[nt] = bias[t * DD + nt * 16 + n16];
                __syncthreads();
            }

            f32x4 acc[8];
            #pragma unroll
            for (int nt = 0; nt < 8; ++nt) acc[nt] = (f32x4){0.f, 0.f, 0.f, 0.f};

            #pragma unroll
            for (int nt = 0; nt < 8; ++nt) {
                #pragma unroll
                for (int kk = 0; kk < 4; ++kk) {
                    bf16x8 b = *(const bf16x8*)&Bs[(((nt << 2) | kk) << 9) | (lane << 3)];
                    acc[nt] = __builtin_amdgcn_mfma_f32_16x16x32_bf16(a[kk], b, acc[nt], 0, 0, 0);
                }
            }

            // epilogue: D[row=q*4+reg][col=nt*16+n16]; 4x64B segments per store
            const int rbase = wrow0 + q * 4;
            bool m0 = true, m1 = true, m2 = true, m3 = true;
            if (tlo != thi) {
                m0 = (tv[rbase + 0] == t);
                m1 = (tv[rbase + 1] == t);
                m2 = (tv[rbase + 2] == t);
                m3 = (tv[rbase + 3] == t);
            }
            float* o = out + (size_t)rbase * DD + n16;
            #pragma unroll
            for (int nt = 0; nt < 8; ++nt) {
                float* oc = o + nt * 16;
                if (m0) oc[0 * DD] = acc[nt][0] + bv[nt];
                if (m1) oc[1 * DD] = acc[nt][1] + bv[nt];
                if (m2) oc[2 * DD] = acc[nt][2] + bv[nt];
                if (m3) oc[3 * DD] = acc[nt][3] + bv[nt];
            }
        }

        // hand prefetch buffer over
        #pragma unroll
        for (int j = 0; j < 8; ++j) xf[j] = xn[j];
    }
}

extern "C" void kernel_launch(void* const* d_in, const int* in_sizes, int n_in,
                              void* d_out, int out_size, void* d_ws, size_t ws_size,
                              hipStream_t stream) {
    const float* x    = (const float*)d_in[0];
    const int*   tv   = (const int*)d_in[1];
    const float* w    = (const float*)d_in[2];
    const float* bias = (const float*)d_in[3];
    float*       out  = (float*)d_out;
    unsigned short* wbf = (unsigned short*)d_ws;   // 512 KB

    int nrows = in_sizes[0] / DD;                  // 131072
    int grid  = nrows / (BM * CHUNK);              // 512

    hipLaunchKernelGGL(transpose_w_frag_kernel, dim3(T_TYPES * 4), dim3(256), 0, stream,
                       w, wbf);
    hipLaunchKernelGGL(hetero_main_kernel, dim3(grid), dim3(256), 0, stream,
                       x, tv, (const __bf16*)wbf, bias, out);
}